// Round 1
// baseline (33621.863 us; speedup 1.0000x reference)
//
#include <hip/hip_runtime.h>

#define IN_DIM 50
#define H1 128
#define H2 128
#define HID 256
#define NGATE 1024
#define N_Y 100
#define STEPS 100
#define BATCH 16384
#define ROWS 64
#define NTHR 256

__device__ __forceinline__ float fast_sigmoid(float x) {
    float e = __expf(-x);
    return __builtin_amdgcn_rcpf(1.0f + e);
}
__device__ __forceinline__ float fast_tanh(float x) {
    // tanh(x) = 1 - 2/(exp(2x)+1); saturates correctly for |x| large
    float e = __expf(2.0f * x);
    return 1.0f - 2.0f * __builtin_amdgcn_rcpf(1.0f + e);
}

// Prep: WgT[k][n] = Wih[n][k] + Whh[n][k]  (k-major so per-k the 4 gate chunks
// of 8 cells are contiguous -> s_load_dwordx8 friendly), bg = bih + bhh.
extern "C" __global__ void prep_kernel(const float* __restrict__ Wih,
                                       const float* __restrict__ Whh,
                                       const float* __restrict__ bih,
                                       const float* __restrict__ bhh,
                                       float* __restrict__ WgT,
                                       float* __restrict__ bg) {
    int idx = blockIdx.x * blockDim.x + threadIdx.x;  // 0 .. 262143
    int n = idx & (NGATE - 1);
    int k = idx >> 10;
    WgT[(size_t)k * NGATE + n] = Wih[(size_t)n * HID + k] + Whh[(size_t)n * HID + k];
    if (idx < NGATE) bg[idx] = bih[idx] + bhh[idx];
}

// One block owns 64 batch rows for the whole computation.
// lane = row (wave-uniform weight addresses -> scalar loads).
// LDS: double-buffered transposed hidden state ht[2][HID][ROWS] = 128 KiB.
// MLP temporaries alias into the two ht buffers (dead by LSTM start).
extern "C" __global__ void __launch_bounds__(NTHR, 1)
rnn_main(const float* __restrict__ x,
         const float* __restrict__ W1, const float* __restrict__ b1,
         const float* __restrict__ W2, const float* __restrict__ b2,
         const float* __restrict__ W3, const float* __restrict__ b3,
         const float* __restrict__ WgT, const float* __restrict__ bg,
         const float* __restrict__ Wo, const float* __restrict__ bo,
         float* __restrict__ out)
{
    __shared__ float lds[2 * HID * ROWS];   // 131072 B
    float* htA = lds;                        // [HID][ROWS]
    float* htB = lds + HID * ROWS;           // [HID][ROWS]

    const int tid  = threadIdx.x;
    const int lane = tid & 63;                                   // row in tile
    const int w    = __builtin_amdgcn_readfirstlane(tid >> 6);   // wave 0..3
    const int r0   = blockIdx.x * ROWS;

    // ---- stage x transposed: xt[k][r] (aliases htA; dead after layer1) ----
    float* xt = htA;
    for (int i = tid; i < ROWS * IN_DIM; i += NTHR) {
        int r = i / IN_DIM, k = i - r * IN_DIM;
        xt[k * ROWS + r] = x[(size_t)(r0 + r) * IN_DIM + k];
    }
    __syncthreads();

    float* h1t = htB;               // [H1][ROWS]
    float* h2t = htB + H1 * ROWS;   // [H2][ROWS]

    // ---- layer 1: h1 = relu(x @ W1^T + b1), 32 neurons per wave ----
    #pragma unroll
    for (int jt = 0; jt < 4; ++jt) {
        const int jb = w * 32 + jt * 8;
        float acc[8];
        #pragma unroll
        for (int jj = 0; jj < 8; ++jj) acc[jj] = b1[jb + jj];
        for (int k = 0; k < IN_DIM; ++k) {
            float h = xt[k * ROWS + lane];
            #pragma unroll
            for (int jj = 0; jj < 8; ++jj)
                acc[jj] = fmaf(h, W1[(jb + jj) * IN_DIM + k], acc[jj]);
        }
        #pragma unroll
        for (int jj = 0; jj < 8; ++jj)
            h1t[(jb + jj) * ROWS + lane] = fmaxf(acc[jj], 0.0f);
    }
    __syncthreads();

    // ---- layer 2 ----
    #pragma unroll
    for (int jt = 0; jt < 4; ++jt) {
        const int jb = w * 32 + jt * 8;
        float acc[8];
        #pragma unroll
        for (int jj = 0; jj < 8; ++jj) acc[jj] = b2[jb + jj];
        for (int k = 0; k < H1; ++k) {
            float h = h1t[k * ROWS + lane];
            #pragma unroll
            for (int jj = 0; jj < 8; ++jj)
                acc[jj] = fmaf(h, W2[(jb + jj) * H1 + k], acc[jj]);
        }
        #pragma unroll
        for (int jj = 0; jj < 8; ++jj)
            h2t[(jb + jj) * ROWS + lane] = fmaxf(acc[jj], 0.0f);
    }
    __syncthreads();

    // ---- layer 3 -> htA (xt dead) and ct registers; 64 cells per wave ----
    float ct[64];
    #pragma unroll
    for (int jt = 0; jt < 8; ++jt) {
        const int jb = w * 64 + jt * 8;
        float acc[8];
        #pragma unroll
        for (int jj = 0; jj < 8; ++jj) acc[jj] = b3[jb + jj];
        for (int k = 0; k < H2; ++k) {
            float h = h2t[k * ROWS + lane];
            #pragma unroll
            for (int jj = 0; jj < 8; ++jj)
                acc[jj] = fmaf(h, W3[(jb + jj) * H2 + k], acc[jj]);
        }
        #pragma unroll
        for (int jj = 0; jj < 8; ++jj) {
            float v = fmaxf(acc[jj], 0.0f);
            htA[(jb + jj) * ROWS + lane] = v;   // h0
            ct[jt * 8 + jj] = v;                // c0 = h0
        }
    }
    __syncthreads();

    // ---- LSTM: 100 steps, 1 barrier per step (double-buffered ht) ----
    for (int t = 0; t < STEPS; ++t) {
        const float* hin = (t & 1) ? htB : htA;
        float*       hout = (t & 1) ? htA : htB;

        #pragma unroll
        for (int jt = 0; jt < 8; ++jt) {
            const int j0 = w * 64 + jt * 8;     // 8 cells this tile
            float ai[8], af[8], ag[8], ao[8];
            #pragma unroll
            for (int jj = 0; jj < 8; ++jj) {
                ai[jj] = bg[      j0 + jj];
                af[jj] = bg[256 + j0 + jj];
                ag[jj] = bg[512 + j0 + jj];
                ao[jj] = bg[768 + j0 + jj];
            }
            const float* hrow = hin + lane;
            #pragma unroll 2
            for (int k = 0; k < HID; ++k) {
                float h = hrow[k * ROWS];                    // conflict-free b32
                const float* wk = WgT + k * NGATE + j0;      // wave-uniform
                #pragma unroll
                for (int jj = 0; jj < 8; ++jj) {
                    ai[jj] = fmaf(h, wk[      jj], ai[jj]);
                    af[jj] = fmaf(h, wk[256 + jj], af[jj]);
                    ag[jj] = fmaf(h, wk[512 + jj], ag[jj]);
                    ao[jj] = fmaf(h, wk[768 + jj], ao[jj]);
                }
            }
            #pragma unroll
            for (int jj = 0; jj < 8; ++jj) {
                float vi = fast_sigmoid(ai[jj]);
                float vf = fast_sigmoid(af[jj]);
                float vg = fast_tanh(ag[jj]);
                float vo = fast_sigmoid(ao[jj]);
                float c  = fmaf(vf, ct[jt * 8 + jj], vi * vg);
                ct[jt * 8 + jj] = c;
                hout[(j0 + jj) * ROWS + lane] = vo * fast_tanh(c);
            }
        }
        __syncthreads();   // hout complete; hin dead

        // ---- y = ht_new @ Wo^T + bo ; 25 outputs per wave ----
        float* orow = out + (size_t)(r0 + lane) * (STEPS * N_Y) + t * N_Y;
        #pragma unroll
        for (int jt = 0; jt < 5; ++jt) {
            const int jy = w * 25 + jt * 5;
            float acc[5];
            #pragma unroll
            for (int jj = 0; jj < 5; ++jj) acc[jj] = bo[jy + jj];
            #pragma unroll 4
            for (int k = 0; k < HID; ++k) {
                float h = hout[k * ROWS + lane];
                #pragma unroll
                for (int jj = 0; jj < 5; ++jj)
                    acc[jj] = fmaf(h, Wo[(jy + jj) * HID + k], acc[jj]);
            }
            #pragma unroll
            for (int jj = 0; jj < 5; ++jj) orow[jy + jj] = acc[jj];
        }
        // no end-of-step barrier needed: next step writes the buffer that the
        // pre-barrier gate phase finished reading; y-phase reads are from the
        // other buffer, which is next written only after the NEXT barrier.
    }
}

extern "C" void kernel_launch(void* const* d_in, const int* in_sizes, int n_in,
                              void* d_out, int out_size, void* d_ws, size_t ws_size,
                              hipStream_t stream) {
    const float* x   = (const float*)d_in[0];
    const float* W1  = (const float*)d_in[1];
    const float* b1  = (const float*)d_in[2];
    const float* W2  = (const float*)d_in[3];
    const float* b2  = (const float*)d_in[4];
    const float* W3  = (const float*)d_in[5];
    const float* b3  = (const float*)d_in[6];
    const float* Wih = (const float*)d_in[7];
    const float* Whh = (const float*)d_in[8];
    const float* bih = (const float*)d_in[9];
    const float* bhh = (const float*)d_in[10];
    const float* Wo  = (const float*)d_in[11];
    const float* bo  = (const float*)d_in[12];
    float* out = (float*)d_out;

    float* WgT = (float*)d_ws;          // [HID][NGATE] = 262144 floats (1 MiB)
    float* bg  = WgT + HID * NGATE;     // [NGATE]

    hipLaunchKernelGGL(prep_kernel, dim3((HID * NGATE) / 256), dim3(256), 0, stream,
                       Wih, Whh, bih, bhh, WgT, bg);
    hipLaunchKernelGGL(rnn_main, dim3(BATCH / ROWS), dim3(NTHR), 0, stream,
                       x, W1, b1, W2, b2, W3, b3, WgT, bg, Wo, bo, out);
}

// Round 6
// 3501.006 us; speedup vs baseline: 9.6035x; 9.6035x over previous
//
#include <hip/hip_runtime.h>

#define IN_DIM 50
#define H1 128
#define H2 128
#define HID 256
#define NGATE 1024
#define N_Y 100
#define NYP 128          // padded y cols
#define STEPS 100
#define BATCH 16384
#define ROWS 64
#define NTHR 512

typedef float f32x16 __attribute__((ext_vector_type(16)));
typedef __bf16 bf16x8 __attribute__((ext_vector_type(8)));
typedef int i32x4 __attribute__((ext_vector_type(4)));

// LDS layout (bytes)
#define CSTRIDE 264                 // cells per row incl. pad (8) -> 528 B rows
#define HHI_OFF 0                   // h_hi [64][264] bf16 = 33792
#define HLO_OFF 33792               // h_lo                 = 33792
#define H2T_OFF 67584               // h2t  [128][64] f32   = 32768
#define SMEM_BYTES 100352

// ws layout (bytes)
#define WGH_OFF 0                   // Wg_hi frag-major: 32 nt x 16 kt x 1024B
#define WGL_OFF 524288
#define WOH_OFF 1048576             // Wo_hi frag-major: 4 nt x 16 kt x 1024B
#define WOL_OFF 1114112
#define BG_OFF  1179648             // f32[1024]
#define BO_OFF  1183744             // f32[128] padded

__device__ __forceinline__ float fast_sigmoid(float x) {
    float e = __expf(-x);
    return __builtin_amdgcn_rcpf(1.0f + e);
}
__device__ __forceinline__ float fast_tanh(float x) {
    float e = __expf(2.0f * x);
    return 1.0f - 2.0f * __builtin_amdgcn_rcpf(1.0f + e);
}
__device__ __forceinline__ unsigned short bf16bits(float x) {
    __bf16 b = (__bf16)x;
    return __builtin_bit_cast(unsigned short, b);
}
__device__ __forceinline__ float bits2f(unsigned short u) {
    __bf16 b = __builtin_bit_cast(__bf16, u);
    return (float)b;
}
__device__ __forceinline__ f32x16 splat16(float v) {
    f32x16 r;
    #pragma unroll
    for (int i = 0; i < 16; ++i) r[i] = v;
    return r;
}

// ---- prep: split weights to bf16 hi/lo in MFMA-fragment-major order ----
// B-frag (32x32x16): lane l holds B[k = kt*16 + (l>>5)*8 + i][n = nt*32 + (l&31)],
// stored contiguously: block (nt*16+kt)*512 + l*8 + i  (bf16 units).
extern "C" __global__ void prep_kernel(const float* __restrict__ Wih,
                                       const float* __restrict__ Whh,
                                       const float* __restrict__ bih,
                                       const float* __restrict__ bhh,
                                       const float* __restrict__ Wo,
                                       const float* __restrict__ bo,
                                       char* __restrict__ ws) {
    int idx = blockIdx.x * blockDim.x + threadIdx.x;
    if (idx < 262144) {                       // Wg = Wih + Whh, [1024][256]
        int n = idx >> 8, k = idx & 255;
        float v = Wih[n * HID + k] + Whh[n * HID + k];
        __bf16 hi = (__bf16)v;
        __bf16 lo = (__bf16)(v - (float)hi);
        int dst = ((n >> 5) * 16 + (k >> 4)) * 512 + ((n & 31) + 32 * ((k >> 3) & 1)) * 8 + (k & 7);
        ((__bf16*)(ws + WGH_OFF))[dst] = hi;
        ((__bf16*)(ws + WGL_OFF))[dst] = lo;
    } else if (idx < 294912) {                // Wo padded to [128][256]
        int j = idx - 262144;
        int n = j >> 8, k = j & 255;
        float v = (n < N_Y) ? Wo[n * HID + k] : 0.0f;
        __bf16 hi = (__bf16)v;
        __bf16 lo = (__bf16)(v - (float)hi);
        int dst = ((n >> 5) * 16 + (k >> 4)) * 512 + ((n & 31) + 32 * ((k >> 3) & 1)) * 8 + (k & 7);
        ((__bf16*)(ws + WOH_OFF))[dst] = hi;
        ((__bf16*)(ws + WOL_OFF))[dst] = lo;
    } else if (idx < 295936) {                // bg
        int n = idx - 294912;
        ((float*)(ws + BG_OFF))[n] = bih[n] + bhh[n];
    } else if (idx < 296064) {                // bo padded
        int n = idx - 295936;
        ((float*)(ws + BO_OFF))[n] = (n < N_Y) ? bo[n] : 0.0f;
    }
}

extern "C" __global__ void __launch_bounds__(NTHR, 2)
rnn_main(const float* __restrict__ x,
         const float* __restrict__ W1, const float* __restrict__ b1,
         const float* __restrict__ W2, const float* __restrict__ b2,
         const float* __restrict__ W3, const float* __restrict__ b3,
         const char* __restrict__ ws,
         float* __restrict__ out)
{
    __shared__ __align__(16) char smem[SMEM_BYTES];

    const int tid  = threadIdx.x;
    const int lane = tid & 63;
    const int lm   = lane & 31;       // MFMA n/m index
    const int l5   = lane >> 5;       // half-wave
    const int w    = __builtin_amdgcn_readfirstlane(tid >> 6);   // wave 0..7
    const int r0   = blockIdx.x * ROWS;

    // ================= MLP prologue (fp32 vector, lane = row) =================
    {
        float* xt  = (float*)(smem + HHI_OFF);   // [50][64]
        float* h1t = (float*)(smem + HLO_OFF);   // [128][64]
        float* h2t = (float*)(smem + H2T_OFF);   // [128][64]

        for (int i = tid; i < ROWS * IN_DIM; i += NTHR) {
            int r = i / IN_DIM, k = i - r * IN_DIM;
            xt[k * ROWS + r] = x[(size_t)(r0 + r) * IN_DIM + k];
        }
        __syncthreads();

        // layer 1: 16 neurons per wave
        #pragma unroll
        for (int jt = 0; jt < 2; ++jt) {
            const int jb = w * 16 + jt * 8;
            float acc[8];
            #pragma unroll
            for (int jj = 0; jj < 8; ++jj) acc[jj] = b1[jb + jj];
            for (int k = 0; k < IN_DIM; ++k) {
                float h = xt[k * ROWS + lane];
                #pragma unroll
                for (int jj = 0; jj < 8; ++jj)
                    acc[jj] = fmaf(h, W1[(jb + jj) * IN_DIM + k], acc[jj]);
            }
            #pragma unroll
            for (int jj = 0; jj < 8; ++jj)
                h1t[(jb + jj) * ROWS + lane] = fmaxf(acc[jj], 0.0f);
        }
        __syncthreads();

        // layer 2
        #pragma unroll
        for (int jt = 0; jt < 2; ++jt) {
            const int jb = w * 16 + jt * 8;
            float acc[8];
            #pragma unroll
            for (int jj = 0; jj < 8; ++jj) acc[jj] = b2[jb + jj];
            for (int k = 0; k < H1; ++k) {
                float h = h1t[k * ROWS + lane];
                #pragma unroll
                for (int jj = 0; jj < 8; ++jj)
                    acc[jj] = fmaf(h, W2[(jb + jj) * H1 + k], acc[jj]);
            }
            #pragma unroll
            for (int jj = 0; jj < 8; ++jj)
                h2t[(jb + jj) * ROWS + lane] = fmaxf(acc[jj], 0.0f);
        }
        __syncthreads();

        // layer 3: 32 cells per wave -> h0 hi/lo bf16 into LDS (row-major)
        unsigned short* hhi = (unsigned short*)(smem + HHI_OFF);
        unsigned short* hlo = (unsigned short*)(smem + HLO_OFF);
        #pragma unroll
        for (int jt = 0; jt < 4; ++jt) {
            const int jb = w * 32 + jt * 8;
            float acc[8];
            #pragma unroll
            for (int jj = 0; jj < 8; ++jj) acc[jj] = b3[jb + jj];
            for (int k = 0; k < H2; ++k) {
                float h = h2t[k * ROWS + lane];
                #pragma unroll
                for (int jj = 0; jj < 8; ++jj)
                    acc[jj] = fmaf(h, W3[(jb + jj) * H2 + k], acc[jj]);
            }
            #pragma unroll
            for (int jj = 0; jj < 8; ++jj) {
                float v = fmaxf(acc[jj], 0.0f);
                unsigned short hb = bf16bits(v);
                unsigned short lb = bf16bits(v - bits2f(hb));
                hhi[lane * CSTRIDE + jb + jj] = hb;   // row = lane, cell = jb+jj
                hlo[lane * CSTRIDE + jb + jj] = lb;
            }
        }
        __syncthreads();
    }

    // ================= LSTM + output projection =================
    const bf16x8* __restrict__ BgH = (const bf16x8*)(ws + WGH_OFF);
    const bf16x8* __restrict__ BgL = (const bf16x8*)(ws + WGL_OFF);
    const bf16x8* __restrict__ BoH = (const bf16x8*)(ws + WOH_OFF);
    const bf16x8* __restrict__ BoL = (const bf16x8*)(ws + WOL_OFF);
    const float*  __restrict__ bg  = (const float*)(ws + BG_OFF);
    const float*  __restrict__ boP = (const float*)(ws + BO_OFF);

    // hoisted per-lane constants
    float bgv[4];
    #pragma unroll
    for (int c = 0; c < 4; ++c) bgv[c] = bg[c * 256 + w * 32 + lm];
    const int yct = w & 3, yrt = w >> 2;
    const float bo_v = boP[yct * 32 + lm];

    // A-fragment base byte offset: row = (l&31), k-half = (l>>5)*8
    const int aoff = lm * (CSTRIDE * 2) + l5 * 16;
    // h-write column byte offset (cell = w*32 + lm)
    const int colb = (w * 32 + lm) * 2;

    // c0 = h0 (reconstruct fp32 from hi+lo), in D-fragment register mapping
    float cst[2][16];
    {
        const unsigned short* hhi = (const unsigned short*)(smem + HHI_OFF);
        const unsigned short* hlo = (const unsigned short*)(smem + HLO_OFF);
        #pragma unroll
        for (int rt = 0; rt < 2; ++rt)
            #pragma unroll
            for (int r = 0; r < 16; ++r) {
                int row = rt * 32 + (r & 3) + 8 * (r >> 2) + 4 * l5;
                int cell = w * 32 + lm;
                cst[rt][r] = bits2f(hhi[row * CSTRIDE + cell]) + bits2f(hlo[row * CSTRIDE + cell]);
            }
    }

    for (int t = 0; t < STEPS; ++t) {
        // ---- gates GEMM: C[64 x 1024] = (h_hi+h_lo) @ (W_hi+W_lo), 3 terms ----
        f32x16 acc[4][2];
        #pragma unroll
        for (int c = 0; c < 4; ++c) {
            acc[c][0] = splat16(bgv[c]);
            acc[c][1] = splat16(bgv[c]);
        }

        #pragma unroll 2
        for (int kk = 0; kk < 16; ++kk) {
            const int kb = kk * 32;    // byte offset along k (16 bf16)
            bf16x8 ah0 = __builtin_bit_cast(bf16x8, *(const i32x4*)(smem + HHI_OFF + aoff + kb));
            bf16x8 ah1 = __builtin_bit_cast(bf16x8, *(const i32x4*)(smem + HHI_OFF + 16896 + aoff + kb));
            bf16x8 al0 = __builtin_bit_cast(bf16x8, *(const i32x4*)(smem + HLO_OFF + aoff + kb));
            bf16x8 al1 = __builtin_bit_cast(bf16x8, *(const i32x4*)(smem + HLO_OFF + 16896 + aoff + kb));
            #pragma unroll
            for (int c = 0; c < 4; ++c) {
                const int fb = ((c * 8 + w) * 16 + kk) * 64 + lane;
                bf16x8 bh = BgH[fb];
                bf16x8 bl = BgL[fb];
                acc[c][0] = __builtin_amdgcn_mfma_f32_32x32x16_bf16(ah0, bh, acc[c][0], 0, 0, 0);
                acc[c][1] = __builtin_amdgcn_mfma_f32_32x32x16_bf16(ah1, bh, acc[c][1], 0, 0, 0);
                acc[c][0] = __builtin_amdgcn_mfma_f32_32x32x16_bf16(al0, bh, acc[c][0], 0, 0, 0);
                acc[c][1] = __builtin_amdgcn_mfma_f32_32x32x16_bf16(al1, bh, acc[c][1], 0, 0, 0);
                acc[c][0] = __builtin_amdgcn_mfma_f32_32x32x16_bf16(ah0, bl, acc[c][0], 0, 0, 0);
                acc[c][1] = __builtin_amdgcn_mfma_f32_32x32x16_bf16(ah1, bl, acc[c][1], 0, 0, 0);
            }
        }

        // ---- elementwise: gates -> c,h ; stash h_new packed (hi|lo<<16) ----
        unsigned int hn[2][16];
        #pragma unroll
        for (int rt = 0; rt < 2; ++rt)
            #pragma unroll
            for (int r = 0; r < 16; ++r) {
                float vi = fast_sigmoid(acc[0][rt][r]);
                float vf = fast_sigmoid(acc[1][rt][r]);
                float vg = fast_tanh(acc[2][rt][r]);
                float vo = fast_sigmoid(acc[3][rt][r]);
                float c  = fmaf(vf, cst[rt][r], vi * vg);
                cst[rt][r] = c;
                float h  = vo * fast_tanh(c);
                unsigned short hb = bf16bits(h);
                unsigned short lb = bf16bits(h - bits2f(hb));
                hn[rt][r] = (unsigned int)hb | ((unsigned int)lb << 16);
            }

        __syncthreads();   // all waves done READING h_old

        #pragma unroll
        for (int rt = 0; rt < 2; ++rt)
            #pragma unroll
            for (int r = 0; r < 16; ++r) {
                int row = rt * 32 + (r & 3) + 8 * (r >> 2) + 4 * l5;
                int ro = row * (CSTRIDE * 2) + colb;
                *(unsigned short*)(smem + HHI_OFF + ro) = (unsigned short)hn[rt][r];
                *(unsigned short*)(smem + HLO_OFF + ro) = (unsigned short)(hn[rt][r] >> 16);
            }

        __syncthreads();   // h_new visible to all waves

        // ---- y = h_new @ Wo^T + bo : wave -> (rt = w>>2, ct = w&3) ----
        f32x16 ya = splat16(bo_v);
        const int yao = yrt * 16896 + aoff;
        #pragma unroll 2
        for (int kk = 0; kk < 16; ++kk) {
            const int kb = kk * 32;
            bf16x8 ah = __builtin_bit_cast(bf16x8, *(const i32x4*)(smem + HHI_OFF + yao + kb));
            bf16x8 al = __builtin_bit_cast(bf16x8, *(const i32x4*)(smem + HLO_OFF + yao + kb));
            const int fb = (yct * 16 + kk) * 64 + lane;
            bf16x8 bh = BoH[fb];
            bf16x8 bl = BoL[fb];
            ya = __builtin_amdgcn_mfma_f32_32x32x16_bf16(ah, bh, ya, 0, 0, 0);
            ya = __builtin_amdgcn_mfma_f32_32x32x16_bf16(al, bh, ya, 0, 0, 0);
            ya = __builtin_amdgcn_mfma_f32_32x32x16_bf16(ah, bl, ya, 0, 0, 0);
        }
        const int col = yct * 32 + lm;
        if (col < N_Y) {
            #pragma unroll
            for (int r = 0; r < 16; ++r) {
                int row = yrt * 32 + (r & 3) + 8 * (r >> 2) + 4 * l5;
                out[(size_t)(r0 + row) * (STEPS * N_Y) + t * N_Y + col] = ya[r];
            }
        }
        // next step's gate reads hit the same (now stable) h buffers; the next
        // write only happens after the next post-GEMM barrier.
    }
}

extern "C" void kernel_launch(void* const* d_in, const int* in_sizes, int n_in,
                              void* d_out, int out_size, void* d_ws, size_t ws_size,
                              hipStream_t stream) {
    const float* x   = (const float*)d_in[0];
    const float* W1  = (const float*)d_in[1];
    const float* b1  = (const float*)d_in[2];
    const float* W2  = (const float*)d_in[3];
    const float* b2  = (const float*)d_in[4];
    const float* W3  = (const float*)d_in[5];
    const float* b3  = (const float*)d_in[6];
    const float* Wih = (const float*)d_in[7];
    const float* Whh = (const float*)d_in[8];
    const float* bih = (const float*)d_in[9];
    const float* bhh = (const float*)d_in[10];
    const float* Wo  = (const float*)d_in[11];
    const float* bo  = (const float*)d_in[12];
    float* out = (float*)d_out;
    char* ws = (char*)d_ws;

    hipLaunchKernelGGL(prep_kernel, dim3(1157), dim3(256), 0, stream,
                       Wih, Whh, bih, bhh, Wo, bo, ws);
    hipLaunchKernelGGL(rnn_main, dim3(BATCH / ROWS), dim3(NTHR), 0, stream,
                       x, W1, b1, W2, b2, W3, b3, ws, out);
}